// Round 18
// baseline (5648.335 us; speedup 1.0000x reference)
//
#include <hip/hip_runtime.h>

// ---------------------------------------------------------------------------
// SNN two-layer SNU — bit-exact to the np referee (identified rounds 0-9):
//   * matmul: per element, fp32 ascending-k FMA chain, single flush (plain
//     f32 add) at k=512   -> two half-K passes, pass2 does C += chain
//   * recurrence: fp32, numpy op order, NO fma contraction
// Round 18: r14's exact geometry (8x8/thread, 128^2 tile, BK=32, gload_lds +
// both-sides XOR swizzle) + (a) macro-based double-buffer (4 static shared
// arrays, kt unrolled by 2 -> compile-time buffers, NO lambdas = no r13/r15
// spill) and (b) XCD-aware block remap (A-panel sharers -> same XCD L2).
// Ascending-k chunk-major order unchanged = bit-exact.
// ---------------------------------------------------------------------------

#define TILE 128
#define BK 32              // floats per tile row = 8 chunks of 16B
#define NTILE (512 / BK)   // 16 k-tiles per half pass

typedef const __attribute__((address_space(1))) void* gptr_t;
typedef __attribute__((address_space(3))) void* sptr_t;

#define STAGE(ktv, AS, BS) do {                                               \
    const int k0s = kbase + (ktv) * BK;                                       \
    _Pragma("unroll")                                                         \
    for (int is = 0; is < 4; ++is) {                                          \
        const int rb   = w * 4 + is;                                          \
        const int srow = rb * 8 + lr8;                                        \
        const int sc   = lc ^ (rb & 7);                                       \
        const float* ga = A + (size_t)(n0 + srow) * K + k0s + sc * 4;         \
        const float* gb = B + (size_t)(m0 + srow) * K + k0s + sc * 4;         \
        __builtin_amdgcn_global_load_lds((gptr_t)ga, (sptr_t)((AS) + rb * 8 * BK), 16, 0, 0); \
        __builtin_amdgcn_global_load_lds((gptr_t)gb, (sptr_t)((BS) + rb * 8 * BK), 16, 0, 0); \
    }                                                                         \
} while (0)

#define COMPUTE(AS, BS) do {                                                  \
    _Pragma("unroll")                                                         \
    for (int c = 0; c < 8; ++c) {                                             \
        float4 bf[8];                                                         \
        _Pragma("unroll")                                                     \
        for (int j = 0; j < 8; ++j)                                           \
            bf[j] = *(const float4*)&(BS)[(col0 + j) * BK + ((c ^ tx) << 2)]; \
        _Pragma("unroll")                                                     \
        for (int i = 0; i < 8; ++i) {                                         \
            float4 af = *(const float4*)&(AS)[(row0 + i) * BK + ((c ^ ty) << 2)]; \
            _Pragma("unroll")                                                 \
            for (int j = 0; j < 8; ++j) {                                     \
                acc[i][j] = __builtin_fmaf(af.x, bf[j].x, acc[i][j]);         \
                acc[i][j] = __builtin_fmaf(af.y, bf[j].y, acc[i][j]);         \
                acc[i][j] = __builtin_fmaf(af.z, bf[j].z, acc[i][j]);         \
                acc[i][j] = __builtin_fmaf(af.w, bf[j].w, acc[i][j]);         \
            }                                                                 \
        }                                                                     \
    }                                                                         \
} while (0)

template<int ADD>
__global__ __launch_bounds__(256) void gemm_nt_db2(
    const float* __restrict__ A,
    const float* __restrict__ B,
    float* __restrict__ C,
    int N, int M, int K, int kbase)
{
#pragma clang fp contract(off)
    __shared__ float As0[TILE * BK];
    __shared__ float Bs0[TILE * BK];
    __shared__ float As1[TILE * BK];
    __shared__ float Bs1[TILE * BK];

    const int tid  = threadIdx.x;
    const int w    = tid >> 6;         // wave 0..3
    const int lane = tid & 63;
    const int tx   = lane & 7;
    const int ty   = lane >> 3;
    const int wr   = w >> 1;
    const int wc   = w & 1;
    const int row0 = wr * 64 + ty * 8;
    const int col0 = wc * 64 + tx * 8;

    // XCD-aware remap: 1600 blocks; the 8 blocks sharing an A panel (same bx)
    // get dispatch ids congruent mod 8 -> same XCD -> A hits that XCD's L2.
    const int id = blockIdx.x;
    const int bx = (id & 7) | ((id >> 6) << 3);   // 0..199
    const int by = (id >> 3) & 7;                 // 0..7
    const int n0 = bx * TILE;
    const int m0 = by * TILE;

    const int lr8 = lane >> 3;
    const int lc  = lane & 7;

    float acc[8][8];
#pragma unroll
    for (int i = 0; i < 8; ++i)
#pragma unroll
        for (int j = 0; j < 8; ++j) acc[i][j] = 0.f;

    STAGE(0, As0, Bs0);
    __syncthreads();                   // buf0 ready

    for (int kt = 0; kt < NTILE; kt += 2) {
        if (kt + 1 < NTILE) STAGE(kt + 1, As1, Bs1);   // fly under compute
        COMPUTE(As0, Bs0);
        __syncthreads();               // drains buf1 stage; seals buf0 reads
        if (kt + 2 < NTILE) STAGE(kt + 2, As0, Bs0);
        COMPUTE(As1, Bs1);             // NTILE even -> kt+1 always valid
        __syncthreads();               // drains buf0 stage; seals buf1 reads
    }

#pragma unroll
    for (int i = 0; i < 8; ++i) {
        size_t row = (size_t)(n0 + row0 + i);
        float* Cp = C + row * M + m0 + col0;
        if (ADD) {
            float4 o0 = *(float4*)Cp;
            float4 o1 = *(float4*)(Cp + 4);
            o0.x = o0.x + acc[i][0]; o0.y = o0.y + acc[i][1];
            o0.z = o0.z + acc[i][2]; o0.w = o0.w + acc[i][3];
            o1.x = o1.x + acc[i][4]; o1.y = o1.y + acc[i][5];
            o1.z = o1.z + acc[i][6]; o1.w = o1.w + acc[i][7];
            *(float4*)Cp       = o0;
            *(float4*)(Cp + 4) = o1;
        } else {
            float4 o0 = {acc[i][0], acc[i][1], acc[i][2], acc[i][3]};
            float4 o1 = {acc[i][4], acc[i][5], acc[i][6], acc[i][7]};
            *(float4*)Cp       = o0;
            *(float4*)(Cp + 4) = o1;
        }
    }
}

// Layer-1 recurrence, float4-vectorized, numpy op order, contraction off.
__global__ __launch_bounds__(256) void scan_l1v(
    const float* __restrict__ Z, const float* __restrict__ bias,
    float* __restrict__ spikes, float* __restrict__ mem, int T, int BH)
{
#pragma clang fp contract(off)
    const int BH4 = BH >> 2;
    int i4 = blockIdx.x * blockDim.x + threadIdx.x;
    if (i4 >= BH4) return;
    const float4* Zv = (const float4*)Z;
    float4* spv  = (float4*)spikes;
    float4* memv = (float4*)mem;
    const float4 bb = *(const float4*)&bias[(i4 << 2) & 1023];

    float4 s = {0.f,0.f,0.f,0.f}, y = {0.f,0.f,0.f,0.f};
    float4 z = Zv[i4];
    for (int t = 0; t < T; ++t) {
        size_t idx = (size_t)t * BH4 + i4;
        float4 zn;
        if (t + 1 < T) zn = Zv[idx + BH4]; else zn = make_float4(0.f,0.f,0.f,0.f);
        float u;
        u = z.x + (0.8f * s.x) * (1.0f - y.x); s.x = fmaxf(u, 0.f); y.x = ((s.x + bb.x) > 0.f) ? 1.f : 0.f;
        u = z.y + (0.8f * s.y) * (1.0f - y.y); s.y = fmaxf(u, 0.f); y.y = ((s.y + bb.y) > 0.f) ? 1.f : 0.f;
        u = z.z + (0.8f * s.z) * (1.0f - y.z); s.z = fmaxf(u, 0.f); y.z = ((s.z + bb.z) > 0.f) ? 1.f : 0.f;
        u = z.w + (0.8f * s.w) * (1.0f - y.w); s.w = fmaxf(u, 0.f); y.w = ((s.w + bb.w) > 0.f) ? 1.f : 0.f;
        spv[idx]  = y;
        memv[idx] = s;
        z = zn;
    }
}

// Layer-2 recurrence, float4-vectorized, in place Z2 -> mem2.
__global__ __launch_bounds__(256) void scan_l2v(
    float* __restrict__ Z, const float* __restrict__ bias, int T, int BH)
{
#pragma clang fp contract(off)
    const int BH4 = BH >> 2;
    int i4 = blockIdx.x * blockDim.x + threadIdx.x;
    if (i4 >= BH4) return;
    float4* Zv = (float4*)Z;
    const float4 bb = *(const float4*)&bias[(i4 << 2) & 1023];

    float4 s = {0.f,0.f,0.f,0.f}, y = {0.f,0.f,0.f,0.f};
    float4 z = Zv[i4];
    for (int t = 0; t < T; ++t) {
        size_t idx = (size_t)t * BH4 + i4;
        float4 zn;
        if (t + 1 < T) zn = Zv[idx + BH4]; else zn = make_float4(0.f,0.f,0.f,0.f);
        float u;
        u = z.x + (0.8f * s.x) * (1.0f - y.x); s.x = fmaxf(u, 0.f); y.x = ((s.x + bb.x) > 0.f) ? 1.f : 0.f;
        u = z.y + (0.8f * s.y) * (1.0f - y.y); s.y = fmaxf(u, 0.f); y.y = ((s.y + bb.y) > 0.f) ? 1.f : 0.f;
        u = z.z + (0.8f * s.z) * (1.0f - y.z); s.z = fmaxf(u, 0.f); y.z = ((s.z + bb.z) > 0.f) ? 1.f : 0.f;
        u = z.w + (0.8f * s.w) * (1.0f - y.w); s.w = fmaxf(u, 0.f); y.w = ((s.w + bb.w) > 0.f) ? 1.f : 0.f;
        Zv[idx] = s;
        z = zn;
    }
}

extern "C" void kernel_launch(void* const* d_in, const int* in_sizes, int n_in,
                              void* d_out, int out_size, void* d_ws, size_t ws_size,
                              hipStream_t stream)
{
    (void)in_sizes; (void)n_in; (void)out_size; (void)d_ws; (void)ws_size;

    const float* x  = (const float*)d_in[0];   // [T,B,IN]
    const float* W1 = (const float*)d_in[1];   // [H,IN]
    const float* b1 = (const float*)d_in[2];   // [H]
    const float* W2 = (const float*)d_in[3];   // [H,H]
    const float* b2 = (const float*)d_in[4];   // [H]
    float* out = (float*)d_out;

    const int T = 100, Bsz = 256, IN = 1024, H = 1024;
    const int N  = T * Bsz;                 // 25600
    const int BH = Bsz * H;                 // 262144
    const size_t TBH = (size_t)T * BH;      // 26214400

    float* spikes = out;                    // output 0
    float* mem1   = out + TBH;              // output 1
    float* zbuf   = out + 2 * TBH;          // Z1 -> Z2 -> mem2 (in place)

    dim3 ggrid((N / TILE) * (H / TILE));    // 1600, XCD-remapped in kernel
    dim3 gblk(256);
    dim3 sgrid((BH / 4) / 256);             // 256 blocks
    dim3 sblk(256);

    // Z1 = X @ W1^T  (two k-half passes, bit-exact KC=512 join)
    gemm_nt_db2<0><<<ggrid, gblk, 0, stream>>>(x, W1, zbuf, N, H, IN, 0);
    gemm_nt_db2<1><<<ggrid, gblk, 0, stream>>>(x, W1, zbuf, N, H, IN, 512);
    // layer-1 scan -> spikes, mem1
    scan_l1v<<<sgrid, sblk, 0, stream>>>(zbuf, b1, spikes, mem1, T, BH);
    // Z2 = spikes @ W2^T
    gemm_nt_db2<0><<<ggrid, gblk, 0, stream>>>(spikes, W2, zbuf, N, H, H, 0);
    gemm_nt_db2<1><<<ggrid, gblk, 0, stream>>>(spikes, W2, zbuf, N, H, H, 512);
    // layer-2 scan in place -> mem2
    scan_l2v<<<sgrid, sblk, 0, stream>>>(zbuf, b2, T, BH);
}

// Round 19
// 1412.460 us; speedup vs baseline: 3.9989x; 3.9989x over previous
//
#include <hip/hip_runtime.h>

// ---------------------------------------------------------------------------
// SNN two-layer SNU — bit-exact to the np referee (identified rounds 0-9):
//   * matmul: per element, fp32 ascending-k FMA chain, single flush (plain
//     f32 add) at k=512
//   * recurrence: fp32, numpy op order, NO fma contraction
// Round 19: r14's proven kernel (8x8/thread, 128^2 tile, BK=32, gload_lds +
// both-sides XOR swizzle, 2-phase) + XCD-aware block remap + both k-halves
// in ONE launch (h1 -> d_ws, scan performs the bit-exact plain add h0+h1).
// Fallback to sequential in-place ADD passes if ws_size is insufficient.
// NO double-buffering (r13/r15/r18 all spilled at VGPR=256).
// ---------------------------------------------------------------------------

#define TILE 128
#define BK 32              // floats per tile row = 8 chunks of 16B
#define NTILE (512 / BK)   // 16 k-tiles per half pass

typedef const __attribute__((address_space(1))) void* gptr_t;
typedef __attribute__((address_space(3))) void* sptr_t;

// MODE 0: C = chain(k-half)           (write)
// MODE 1: C = C + chain(k-half)       (in-place add join, fallback path)
// Grid is 1D. SPLITK=1: id encodes (bx, by, kh) XCD-contiguously and the
// kernel writes half kh to C0 (kh=0) / C1 (kh=1).
template<int MODE, int SPLITK>
__global__ __launch_bounds__(256) void gemm_nt_swz(
    const float* __restrict__ A,
    const float* __restrict__ B,
    float* __restrict__ C0,
    float* __restrict__ C1,
    int N, int M, int K, int kbase_arg)
{
#pragma clang fp contract(off)
    __shared__ float As[TILE * BK];   // [row][32], chunk-swizzled
    __shared__ float Bs[TILE * BK];

    const int tid  = threadIdx.x;
    const int w    = tid >> 6;         // wave 0..3
    const int lane = tid & 63;
    const int tx   = lane & 7;
    const int ty   = lane >> 3;
    const int wr   = w >> 1;
    const int wc   = w & 1;
    const int row0 = wr * 64 + ty * 8;
    const int col0 = wc * 64 + tx * 8;

    // XCD-aware decode: xcd = id&7; all blocks of one bx-group share it.
    int bx, by, kbase;
    float* C;
    if (SPLITK) {
        const int id  = blockIdx.x;        // 0..3199
        const int xcd = id & 7;
        const int s   = id >> 3;           // 0..399
        const int r   = s & 15;
        bx    = ((s >> 4) << 3) | xcd;     // 0..199
        by    = r & 7;
        kbase = (r >> 3) ? 512 : 0;
        C     = (r >> 3) ? C1 : C0;
    } else {
        const int id  = blockIdx.x;        // 0..1599
        const int xcd = id & 7;
        const int s   = id >> 3;           // 0..199
        bx    = ((s >> 3) << 3) | xcd;     // 0..199
        by    = s & 7;
        kbase = kbase_arg;
        C     = C0;
    }
    const int n0 = bx * TILE;
    const int m0 = by * TILE;

    const int lr8 = lane >> 3;         // row within 8-row issue block
    const int lc  = lane & 7;          // LDS chunk slot

    float acc[8][8];
#pragma unroll
    for (int i = 0; i < 8; ++i)
#pragma unroll
        for (int j = 0; j < 8; ++j) acc[i][j] = 0.f;

    for (int kt = 0; kt < NTILE; ++kt) {
        const int k0 = kbase + kt * BK;
        __syncthreads();   // previous compute done reading LDS
#pragma unroll
        for (int is = 0; is < 4; ++is) {
            const int rb   = w * 4 + is;              // 8-row block 0..15
            const int srow = rb * 8 + lr8;
            const int sc   = lc ^ (rb & 7);           // inverse-swizzled chunk
            const float* ga = A + (size_t)(n0 + srow) * K + k0 + sc * 4;
            const float* gb = B + (size_t)(m0 + srow) * K + k0 + sc * 4;
            __builtin_amdgcn_global_load_lds((gptr_t)ga, (sptr_t)(As + rb * 8 * BK), 16, 0, 0);
            __builtin_amdgcn_global_load_lds((gptr_t)gb, (sptr_t)(Bs + rb * 8 * BK), 16, 0, 0);
        }
        __syncthreads();   // drains vmcnt(0): tile ready

#pragma unroll
        for (int c = 0; c < 8; ++c) {                 // k-chunk, ascending
            float4 bf[8];
#pragma unroll
            for (int j = 0; j < 8; ++j)
                bf[j] = *(const float4*)&Bs[(col0 + j) * BK + ((c ^ tx) << 2)];
#pragma unroll
            for (int i = 0; i < 8; ++i) {
                float4 af = *(const float4*)&As[(row0 + i) * BK + ((c ^ ty) << 2)];
#pragma unroll
                for (int j = 0; j < 8; ++j) {
                    acc[i][j] = __builtin_fmaf(af.x, bf[j].x, acc[i][j]);
                    acc[i][j] = __builtin_fmaf(af.y, bf[j].y, acc[i][j]);
                    acc[i][j] = __builtin_fmaf(af.z, bf[j].z, acc[i][j]);
                    acc[i][j] = __builtin_fmaf(af.w, bf[j].w, acc[i][j]);
                }
            }
        }
    }

#pragma unroll
    for (int i = 0; i < 8; ++i) {
        size_t row = (size_t)(n0 + row0 + i);
        float* Cp = C + row * M + m0 + col0;
        if (MODE == 1) {
            float4 o0 = *(float4*)Cp;
            float4 o1 = *(float4*)(Cp + 4);
            o0.x = o0.x + acc[i][0]; o0.y = o0.y + acc[i][1];
            o0.z = o0.z + acc[i][2]; o0.w = o0.w + acc[i][3];
            o1.x = o1.x + acc[i][4]; o1.y = o1.y + acc[i][5];
            o1.z = o1.z + acc[i][6]; o1.w = o1.w + acc[i][7];
            *(float4*)Cp       = o0;
            *(float4*)(Cp + 4) = o1;
        } else {
            float4 o0 = {acc[i][0], acc[i][1], acc[i][2], acc[i][3]};
            float4 o1 = {acc[i][4], acc[i][5], acc[i][6], acc[i][7]};
            *(float4*)Cp       = o0;
            *(float4*)(Cp + 4) = o1;
        }
    }
}

// Layer-1 scan. HSUM=1: z = zh0 + zh1 (the bit-exact KC=512 chain join).
template<int HSUM>
__global__ __launch_bounds__(256) void scan_l1v(
    const float* __restrict__ Z0, const float* __restrict__ Z1,
    const float* __restrict__ bias,
    float* __restrict__ spikes, float* __restrict__ mem, int T, int BH)
{
#pragma clang fp contract(off)
    const int BH4 = BH >> 2;
    int i4 = blockIdx.x * blockDim.x + threadIdx.x;
    if (i4 >= BH4) return;
    const float4* Zv0 = (const float4*)Z0;
    const float4* Zv1 = (const float4*)Z1;
    float4* spv  = (float4*)spikes;
    float4* memv = (float4*)mem;
    const float4 bb = *(const float4*)&bias[(i4 << 2) & 1023];

    float4 s = {0.f,0.f,0.f,0.f}, y = {0.f,0.f,0.f,0.f};
    for (int t = 0; t < T; ++t) {
        size_t idx = (size_t)t * BH4 + i4;
        float4 z = Zv0[idx];
        if (HSUM) {
            float4 h1 = Zv1[idx];
            z.x = z.x + h1.x; z.y = z.y + h1.y;
            z.z = z.z + h1.z; z.w = z.w + h1.w;
        }
        float u;
        u = z.x + (0.8f * s.x) * (1.0f - y.x); s.x = fmaxf(u, 0.f); y.x = ((s.x + bb.x) > 0.f) ? 1.f : 0.f;
        u = z.y + (0.8f * s.y) * (1.0f - y.y); s.y = fmaxf(u, 0.f); y.y = ((s.y + bb.y) > 0.f) ? 1.f : 0.f;
        u = z.z + (0.8f * s.z) * (1.0f - y.z); s.z = fmaxf(u, 0.f); y.z = ((s.z + bb.z) > 0.f) ? 1.f : 0.f;
        u = z.w + (0.8f * s.w) * (1.0f - y.w); s.w = fmaxf(u, 0.f); y.w = ((s.w + bb.w) > 0.f) ? 1.f : 0.f;
        spv[idx]  = y;
        memv[idx] = s;
    }
}

// Layer-2 scan, writes mem2 in place over Z0.
template<int HSUM>
__global__ __launch_bounds__(256) void scan_l2v(
    float* __restrict__ Z0, const float* __restrict__ Z1,
    const float* __restrict__ bias, int T, int BH)
{
#pragma clang fp contract(off)
    const int BH4 = BH >> 2;
    int i4 = blockIdx.x * blockDim.x + threadIdx.x;
    if (i4 >= BH4) return;
    float4* Zv0 = (float4*)Z0;
    const float4* Zv1 = (const float4*)Z1;
    const float4 bb = *(const float4*)&bias[(i4 << 2) & 1023];

    float4 s = {0.f,0.f,0.f,0.f}, y = {0.f,0.f,0.f,0.f};
    for (int t = 0; t < T; ++t) {
        size_t idx = (size_t)t * BH4 + i4;
        float4 z = Zv0[idx];
        if (HSUM) {
            float4 h1 = Zv1[idx];
            z.x = z.x + h1.x; z.y = z.y + h1.y;
            z.z = z.z + h1.z; z.w = z.w + h1.w;
        }
        float u;
        u = z.x + (0.8f * s.x) * (1.0f - y.x); s.x = fmaxf(u, 0.f); y.x = ((s.x + bb.x) > 0.f) ? 1.f : 0.f;
        u = z.y + (0.8f * s.y) * (1.0f - y.y); s.y = fmaxf(u, 0.f); y.y = ((s.y + bb.y) > 0.f) ? 1.f : 0.f;
        u = z.z + (0.8f * s.z) * (1.0f - y.z); s.z = fmaxf(u, 0.f); y.z = ((s.z + bb.z) > 0.f) ? 1.f : 0.f;
        u = z.w + (0.8f * s.w) * (1.0f - y.w); s.w = fmaxf(u, 0.f); y.w = ((s.w + bb.w) > 0.f) ? 1.f : 0.f;
        Zv0[idx] = s;
    }
}

extern "C" void kernel_launch(void* const* d_in, const int* in_sizes, int n_in,
                              void* d_out, int out_size, void* d_ws, size_t ws_size,
                              hipStream_t stream)
{
    (void)in_sizes; (void)n_in; (void)out_size;

    const float* x  = (const float*)d_in[0];   // [T,B,IN]
    const float* W1 = (const float*)d_in[1];   // [H,IN]
    const float* b1 = (const float*)d_in[2];   // [H]
    const float* W2 = (const float*)d_in[3];   // [H,H]
    const float* b2 = (const float*)d_in[4];   // [H]
    float* out = (float*)d_out;

    const int T = 100, Bsz = 256, IN = 1024, H = 1024;
    const int N  = T * Bsz;                 // 25600
    const int BH = Bsz * H;                 // 262144
    const size_t TBH = (size_t)T * BH;      // 26214400

    float* spikes = out;                    // output 0
    float* mem1   = out + TBH;              // output 1
    float* zbuf   = out + 2 * TBH;          // h0 buffer -> mem2 (in place)

    dim3 gblk(256);
    dim3 sgrid((BH / 4) / 256);
    dim3 sblk(256);

    const bool hasws = ws_size >= TBH * sizeof(float);

    if (hasws) {
        float* zws = (float*)d_ws;          // h1 buffer
        dim3 ggrid(3200);                   // both k-halves, XCD-remapped
        // Layer 1
        gemm_nt_swz<0,1><<<ggrid, gblk, 0, stream>>>(x, W1, zbuf, zws, N, H, IN, 0);
        scan_l1v<1><<<sgrid, sblk, 0, stream>>>(zbuf, zws, b1, spikes, mem1, T, BH);
        // Layer 2
        gemm_nt_swz<0,1><<<ggrid, gblk, 0, stream>>>(spikes, W2, zbuf, zws, N, H, H, 0);
        scan_l2v<1><<<sgrid, sblk, 0, stream>>>(zbuf, zws, b2, T, BH);
    } else {
        dim3 ggrid(1600);                   // sequential halves, XCD-remapped
        gemm_nt_swz<0,0><<<ggrid, gblk, 0, stream>>>(x, W1, zbuf, nullptr, N, H, IN, 0);
        gemm_nt_swz<1,0><<<ggrid, gblk, 0, stream>>>(x, W1, zbuf, nullptr, N, H, IN, 512);
        scan_l1v<0><<<sgrid, sblk, 0, stream>>>(zbuf, nullptr, b1, spikes, mem1, T, BH);
        gemm_nt_swz<0,0><<<ggrid, gblk, 0, stream>>>(spikes, W2, zbuf, nullptr, N, H, H, 0);
        gemm_nt_swz<1,0><<<ggrid, gblk, 0, stream>>>(spikes, W2, zbuf, nullptr, N, H, H, 512);
        scan_l2v<0><<<sgrid, sblk, 0, stream>>>(zbuf, nullptr, b2, T, BH);
    }
}